// Round 5
// baseline (239.466 us; speedup 1.0000x reference)
//
#include <hip/hip_runtime.h>
#include <math.h>

// VQ quantizer: z [N,64] fp32, codebook [512,64] fp32.
// out layout (all fp32): q_ste [N*64] | loss [1] | ids-as-float [N]
//
// R1-R4: fp32-VALU ladder, 374us. R5: split-bf16 (hh+hl+lh) MFMA computes
// s = z.c - 0.5*|c|^2 (~1e-6 err); rows with best-vs-runnerup margin > STH
// provably match the fp32 argmin; rest -> exact fallback. 377us.
// R6/R7: reg pipeline, 372 (occupancy halved, latency-bound on L2 frags).
// R8: 128KB LDS codebook staging, 5-inst... 214.6us total: vq_mfma 96us
// (MfmaUtil 22.5, VALUBusy 43.5 = 2:1 scan:MFMA issue, 4.46M LDS bank
// conflicts from 4-way wave-level aliasing), BUT 118us sat OUTSIDE vq_mfma:
// 5 dispatches x ~10-15us harness overhead + prep's 8-block latency floor +
// fallback dispatch. R9 (this): ONE kernel + 8B memset.
//  (a) per-block codebook conversion during LDS fill (prep gone);
//  (b) inline wave-cooperative exact fallback via __ballot over uncertain
//      cols (~1150 rows total at STH=2e-4; chains BIT-IDENTICAL to R4/R7);
//  (c) loss finalize by last block (done-counter + threadfence + atomic read);
//  (d) fragment-order LDS layout [T][s][h][col]: every ds_read_b128/write is
//      64 lanes x consecutive 16B -> zero bank conflicts, no swizzle;
//  (e) -0.5c^2 folded into acc0 init (uniform f32x16 LDS broadcast) -> scan
//      5 insts/value;
//  (f) 1024-thr blocks (16 waves, grid 256, 2 row-iters): ~4 waves/SIMD at
//      the same 133KB LDS (launch_bounds VGPR cap 128 - single-buffered frags).
//
// mfma_f32_32x32x16_bf16, A=codebook(M=32 cw), B=z(N=32 rows):
//   C/D: col=lane&31 (z-row), row=(reg&3)+8*(reg>>2)+4*(lane>>5) (codeword)
//   -> per-lane 16 accs are 16 codewords of the lane's OWN row.

constexpr int D     = 64;
constexpr int D4    = 16;      // float4s per row
constexpr int K     = 512;
constexpr float STH = 2e-4f;   // certainty margin in s-space (d-gap = 2*s-gap)

typedef __attribute__((ext_vector_type(8)))  short s16x8;
typedef __attribute__((ext_vector_type(16))) float f32x16;

#define FMA4(acc, zz, cc) do { \
  acc = fmaf((zz).x, (cc).x, acc); \
  acc = fmaf((zz).y, (cc).y, acc); \
  acc = fmaf((zz).z, (cc).z, acc); \
  acc = fmaf((zz).w, (cc).w, acc); } while (0)

#define MFMA_B(A, B, C) __builtin_amdgcn_mfma_f32_32x32x16_bf16(A, B, C, 0, 0, 0)

__device__ __forceinline__ unsigned short f2bf(float f) {
  unsigned u = __float_as_uint(f);
  return (unsigned short)((u + 0x7FFFu + ((u >> 16) & 1u)) >> 16);
}

// LDS map (dynamic, 133120 B):
//   [0,65536)       cbh frags:  addr = T*4096 + s*1024 + h*512 + col*16
//   [65536,131072)  cbl frags:  same order, +65536
//   [131072,133120) nhc2 floats, arranged[t*32 + h*16 + r] = -0.5*c2(perm)
__global__ __launch_bounds__(1024)
void vq_main(const float* __restrict__ z, const float* __restrict__ cbk,
             float* __restrict__ out, float* __restrict__ lossAcc,
             unsigned* __restrict__ done, int N)
{
  extern __shared__ char smem[];

  const int tid  = threadIdx.x;
  const int lane = tid & 63;
  const int wave = tid >> 6;
  const int col  = lane & 31;    // this lane's z-row within the wave's 32 rows
  const int h    = lane >> 5;    // k-half / output split

  // ---- fill: convert codebook -> bf16 hi/lo frag-order tables + nhc2 ------
  // thread t handles half a codeword: cw = t>>1, dims [32*(t&1), +32).
  {
    const int cw   = tid >> 1;
    const int half = tid & 1;
    const float4* c4 = (const float4*)(cbk + (size_t)cw * D) + half * 8;
    float4 f[8];
    #pragma unroll
    for (int i = 0; i < 8; ++i) f[i] = c4[i];
    float pc2 = 0.f;
    #pragma unroll
    for (int i = 0; i < 8; ++i) FMA4(pc2, f[i], f[i]);
    float e[32];
    #pragma unroll
    for (int i = 0; i < 8; ++i) {
      e[4*i] = f[i].x; e[4*i+1] = f[i].y; e[4*i+2] = f[i].z; e[4*i+3] = f[i].w;
    }
    const int T = cw >> 5, cc = cw & 31;
    #pragma unroll
    for (int sl = 0; sl < 2; ++sl) {
      #pragma unroll
      for (int h2 = 0; h2 < 2; ++h2) {
        const int ld0 = sl * 16 + h2 * 8;
        s16x8 vh, vl;
        #pragma unroll
        for (int j = 0; j < 8; ++j) {
          unsigned short hb = f2bf(e[ld0 + j]);
          float hf = __uint_as_float((unsigned)hb << 16);
          vh[j] = (short)hb;
          vl[j] = (short)f2bf(e[ld0 + j] - hf);
        }
        const int a = T * 4096 + (2 * half + sl) * 1024 + h2 * 512 + cc * 16;
        *(s16x8*)(smem + a) = vh;
        *(s16x8*)(smem + 65536 + a) = vl;
      }
    }
    float c2full = pc2 + __shfl_xor(pc2, 1, 64);  // lo+hi on half==0 thread
    if (half == 0) {
      // invert perm(r,h) = (r&3) + 8*(r>>2) + 4*h : arranged[t*32 + h*16 + r]
      const int ai = (T << 5) + (((cc >> 2) & 1) << 4) + ((cc >> 3) << 2) + (cc & 3);
      *(float*)(smem + 131072 + ai * 4) = -0.5f * c2full;
    }
  }
  __syncthreads();   // tables read-only afterwards: no more barriers

  float lacc = 0.f;

  #pragma unroll 1
  for (int it = 0; it < 2; ++it) {
    const long rowg = (long)blockIdx.x * 1024 + it * 512 + wave * 32 + col;

    // z row -> bf16 hi/lo B-frags. Lane holds k = 16s + 8h + j, j=0..7.
    const float4* zp4 = (const float4*)(z + (size_t)rowg * D);
    s16x8 zh[4], zl[4];
    #pragma unroll
    for (int s = 0; s < 4; ++s) {
      float4 p0 = zp4[4 * s + 2 * h];
      float4 p1 = zp4[4 * s + 2 * h + 1];
      float e[8] = {p0.x, p0.y, p0.z, p0.w, p1.x, p1.y, p1.z, p1.w};
      #pragma unroll
      for (int j = 0; j < 8; ++j) {
        unsigned short hb = f2bf(e[j]);
        float hf = __uint_as_float((unsigned)hb << 16);
        zh[s][j] = (short)hb;
        zl[s][j] = (short)f2bf(e[j] - hf);
      }
    }

    float m1 = -INFINITY, m2 = -INFINITY;
    int rbest = 0, tbest = 0;

    #pragma unroll 1
    for (int t = 0; t < 16; ++t) {
      const int fb = t * 4096 + h * 512 + col * 16;
      const s16x8 ch0 = *(const s16x8*)(smem + fb);
      const s16x8 ch1 = *(const s16x8*)(smem + fb + 1024);
      const s16x8 ch2 = *(const s16x8*)(smem + fb + 2048);
      const s16x8 ch3 = *(const s16x8*)(smem + fb + 3072);
      const s16x8 cl0 = *(const s16x8*)(smem + 65536 + fb);
      const s16x8 cl1 = *(const s16x8*)(smem + 65536 + fb + 1024);
      const s16x8 cl2 = *(const s16x8*)(smem + 65536 + fb + 2048);
      const s16x8 cl3 = *(const s16x8*)(smem + 65536 + fb + 3072);

      // acc0 init = permuted -0.5*c2 (uniform broadcast, folds the gg add)
      f32x16 acc0 = *(const f32x16*)(smem + 131072 + (t * 32 + h * 16) * 4);
      f32x16 acc1 = {};
      acc0 = MFMA_B(ch0, zh[0], acc0);  acc1 = MFMA_B(ch1, zh[1], acc1);
      acc0 = MFMA_B(ch2, zh[2], acc0);  acc1 = MFMA_B(ch3, zh[3], acc1);
      acc0 = MFMA_B(ch0, zl[0], acc0);  acc1 = MFMA_B(ch1, zl[1], acc1);
      acc0 = MFMA_B(ch2, zl[2], acc0);  acc1 = MFMA_B(ch3, zl[3], acc1);
      acc0 = MFMA_B(cl0, zh[0], acc0);  acc1 = MFMA_B(cl1, zh[1], acc1);
      acc0 = MFMA_B(cl2, zh[2], acc0);  acc1 = MFMA_B(cl3, zh[3], acc1);

      // scan: two 8-chains + exact max/med merge (R8-verified logic, gg gone)
      float m1a = -INFINITY, m2a = -INFINITY, m1b = -INFINITY, m2b = -INFINITY;
      int ra_ = 0, rb_ = 8;
      #pragma unroll
      for (int r = 0; r < 8; ++r) {
        float v = acc0[r] + acc1[r];       // s = dot - 0.5*c2 (c2 in acc0 init)
        bool gt = v > m1a;                 // strict: ties keep earliest
        m2a = fminf(fmaxf(v, m2a), m1a);   // med3: second-best (uses OLD m1)
        if (gt) ra_ = r;
        m1a = gt ? v : m1a;
      }
      #pragma unroll
      for (int r = 8; r < 16; ++r) {
        float v = acc0[r] + acc1[r];
        bool gt = v > m1b;
        m2b = fminf(fmaxf(v, m2b), m1b);
        if (gt) rb_ = r;
        m1b = gt ? v : m1b;
      }
      // perm(r,h) monotone in r -> a-half holds the lower codewords
      float tm1 = fmaxf(m1a, m1b);
      float tm2 = fmaxf(fminf(m1a, m1b), fmaxf(m2a, m2b));
      int   tr_ = (m1b > m1a) ? rb_ : ra_;   // strict: ties keep lower r
      bool tgt = tm1 > m1;                   // strict: ties keep earlier tile
      m2 = fmaxf(fminf(tm1, m1), fmaxf(tm2, m2));
      if (tgt) { rbest = tr_; tbest = t; }
      m1 = tgt ? tm1 : m1;
    }

    // cw index from (tile, reg, half): perm(r,h) = (r&3) + 8*(r>>2) + 4h
    int idx = (tbest << 5) + (h << 2) + (rbest & 3) + ((rbest >> 2) << 3);

    // combine the two k-halves (lane <-> lane^32); lower cw wins ties
    float om1  = __shfl_xor(m1, 32);
    float om2  = __shfl_xor(m2, 32);
    int   oidx = __shfl_xor(idx, 32);
    float nm2 = fmaxf(fminf(m1, om1), fmaxf(m2, om2));
    bool take = (om1 > m1) || ((om1 == m1) && (oidx < idx));
    if (take) { m1 = om1; idx = oidx; }
    m2 = nm2;

    const bool certain = (m1 - m2 > STH);
    if (certain) {
      // provably the fp32 argmin. Epilogue ops identical to R4, split across
      // the lane pair (h picks the 32-element half of the row).
      const float4* qp = (const float4*)(cbk + (size_t)idx * D) + (h << 3);
      const float4* zp = (const float4*)(z + (size_t)rowg * D) + (h << 3);
      float4*       op = (float4*)(out + (size_t)rowg * D) + (h << 3);
      #pragma unroll
      for (int i = 0; i < 8; ++i) {
        float4 q = qp[i], zz = zp[i], u, qs;
        u.x = q.x - zz.x; u.y = q.y - zz.y; u.z = q.z - zz.z; u.w = q.w - zz.w;
        qs.x = zz.x + u.x; qs.y = zz.y + u.y; qs.z = zz.z + u.z; qs.w = zz.w + u.w;
        FMA4(lacc, u, u);
        op[i] = qs;
      }
      if (h == 0) (out + (size_t)N * D + 1)[rowg] = (float)idx;
    }

    // ---- inline exact fallback: wave cooperates on each uncertain col ----
    // Per-(row,k) chains BIT-IDENTICAL to R4/R7 (c2: FMA4 i=0..15 in order;
    // a0 = even chunks, b0 = odd chunks in order; d = fmaf(-2,dot,z2)+c2).
    // Cross-lane merge: min-d, tie -> lowest k == numpy first-min.
    unsigned mask32 = (unsigned)__ballot((!certain) && h == 0);
    while (mask32) {
      const int c = __builtin_ctz(mask32);
      mask32 &= mask32 - 1;
      const size_t r0 = (size_t)blockIdx.x * 1024 + it * 512 + wave * 32 + c;
      const float4* zp = (const float4*)(z + r0 * D);
      float4 z0[D4];
      #pragma unroll
      for (int i = 0; i < D4; ++i) z0[i] = zp[i];
      float z2 = 0.f;
      #pragma unroll
      for (int i = 0; i < D4; ++i) FMA4(z2, z0[i], z0[i]);

      float best = INFINITY;
      int   bi = 0;
      #pragma unroll 1
      for (int j = 0; j < 8; ++j) {
        const int k = (lane << 3) + j;
        const float4* c4 = (const float4*)(cbk + (size_t)k * D);
        float c2 = 0.f, a0 = 0.f, b0 = 0.f;
        float4 cr[8];
        #pragma unroll
        for (int i = 0; i < 8; ++i) cr[i] = c4[i];
        #pragma unroll
        for (int i = 0; i < 8; ++i) FMA4(c2, cr[i], cr[i]);
        #pragma unroll
        for (int i = 0; i < 4; ++i) {
          FMA4(a0, z0[2 * i],     cr[2 * i]);
          FMA4(b0, z0[2 * i + 1], cr[2 * i + 1]);
        }
        #pragma unroll
        for (int i = 0; i < 8; ++i) cr[i] = c4[8 + i];
        #pragma unroll
        for (int i = 0; i < 8; ++i) FMA4(c2, cr[i], cr[i]);
        #pragma unroll
        for (int i = 0; i < 4; ++i) {
          FMA4(a0, z0[8 + 2 * i], cr[2 * i]);
          FMA4(b0, z0[9 + 2 * i], cr[2 * i + 1]);
        }
        float dot = a0 + b0;
        float d = fmaf(-2.f, dot, z2) + c2;
        if (d < best) { best = d; bi = k; }   // strict <, ascending k
      }

      #pragma unroll
      for (int off = 32; off > 0; off >>= 1) {
        float ob = __shfl_xor(best, off, 64);
        int  obi = __shfl_xor(bi, off, 64);
        if (ob < best || (ob == best && obi < bi)) { best = ob; bi = obi; }
      }

      if (lane == 0) {
        const float4* qp = (const float4*)(cbk + (size_t)bi * D);
        float4* o = (float4*)(out + r0 * D);
        #pragma unroll
        for (int i = 0; i < D4; ++i) {
          float4 q = qp[i], zz = z0[i], u, qs;
          u.x = q.x - zz.x; u.y = q.y - zz.y; u.z = q.z - zz.z; u.w = q.w - zz.w;
          qs.x = zz.x + u.x; qs.y = zz.y + u.y; qs.z = zz.z + u.z; qs.w = zz.w + u.w;
          FMA4(lacc, u, u);
          o[i] = qs;
        }
        (out + (size_t)N * D + 1)[r0] = (float)bi;
      }
    }
  }

  // loss: wave shuffle reduce -> one atomicAdd per wave; last block finalizes.
  #pragma unroll
  for (int off = 32; off > 0; off >>= 1) lacc += __shfl_down(lacc, off, 64);
  if (lane == 0) atomicAdd(lossAcc, lacc);
  __syncthreads();
  if (tid == 0) {
    __threadfence();                               // publish this block's adds
    unsigned d = atomicAdd(done, 1u);
    if (d == gridDim.x - 1) {                      // last block: all adds done
      float total = atomicAdd(lossAcc, 0.0f);      // device-scope atomic read
      out[(size_t)N * D] = 1.25f * (total / (float)((long)N * D));
    }
  }
}

extern "C" void kernel_launch(void* const* d_in, const int* in_sizes, int n_in,
                              void* d_out, int out_size, void* d_ws, size_t ws_size,
                              hipStream_t stream)
{
  const float* z   = (const float*)d_in[0];
  const float* cbk = (const float*)d_in[1];
  float* out = (float*)d_out;
  float* ws  = (float*)d_ws;
  const int N = in_sizes[0] / D;

  // ws layout (floats): [0]=lossAcc, [1]=done counter
  float*    lossAcc = ws;
  unsigned* done    = (unsigned*)(ws + 1);

  hipMemsetAsync(ws, 0, 8, stream);  // clears lossAcc + done
  vq_main<<<N / 1024, 1024, 133120, stream>>>(z, cbk, out, lossAcc, done, N);
}

// Round 6
// 225.661 us; speedup vs baseline: 1.0612x; 1.0612x over previous
//
#include <hip/hip_runtime.h>
#include <math.h>

// VQ quantizer: z [N,64] fp32, codebook [512,64] fp32.
// out layout (all fp32): q_ste [N*64] | loss [1] | ids-as-float [N]
//
// R1-R4: fp32-VALU ladder, 374us. R5: split-bf16 (hh+hl+lh) MFMA computes
// s = z.c - 0.5*|c|^2; rows with best-vs-runnerup margin > STH provably match
// the fp32 argmin; rest -> exact fallback. R8: 128KB LDS codebook staging,
// 512thr, double-buffered LDS prefetch: vq_mfma 96us but 118us outside
// (5 dispatches). R9: fused to ONE kernel (fill+scan+inline fallback+finalize)
// -- fusion worked (gap 118->88us) BUT (a) launch_bounds(1024) capped VGPR at
// 64 -> fallback spilled to scratch (+76MB HBM traffic), (b) dropped the
// 1-tile-ahead prefetch (MfmaUtil 22.5->13.6). 239us.
// R10 (this): R8's engine in R9's shell.
//  - 512 thr (8 waves), 256 blocks, 4 row-iters; LDS-bound at 1 block/CU so
//    launch_bounds(512,2) gives a 256-VGPR budget -> fallback fits, no spill.
//  - double-buffered LDS_FRAGS + LDS_GG prefetch (R8-verified pipeline).
//  - frag-order LDS layout [T][s][h][col] (R9-verified ~0 conflicts).
//  - acc0 init from prefetched gg regs (scan 5 insts/value, no per-value add).
//  - fill: one thread = one codeword (512/512), conversion fused.
//  - inline wave-cooperative exact fallback (chains BIT-IDENTICAL to R4/R7);
//    loss finalized by last block via done-counter. 2 dispatches total.
//
// mfma_f32_32x32x16_bf16, A=codebook(M=32 cw), B=z(N=32 rows):
//   C/D: col=lane&31 (z-row), row=(reg&3)+8*(reg>>2)+4*(lane>>5) (codeword)
//   -> per-lane 16 accs are 16 codewords of the lane's OWN row.

constexpr int D     = 64;
constexpr int D4    = 16;      // float4s per row
constexpr int K     = 512;
constexpr float STH = 2e-4f;   // certainty margin in s-space (d-gap = 2*s-gap)

typedef __attribute__((ext_vector_type(8)))  short s16x8;
typedef __attribute__((ext_vector_type(16))) float f32x16;

#define FMA4(acc, zz, cc) do { \
  acc = fmaf((zz).x, (cc).x, acc); \
  acc = fmaf((zz).y, (cc).y, acc); \
  acc = fmaf((zz).z, (cc).z, acc); \
  acc = fmaf((zz).w, (cc).w, acc); } while (0)

#define MFMA_B(A, B, C) __builtin_amdgcn_mfma_f32_32x32x16_bf16(A, B, C, 0, 0, 0)

__device__ __forceinline__ unsigned short f2bf(float f) {
  unsigned u = __float_as_uint(f);
  return (unsigned short)((u + 0x7FFFu + ((u >> 16) & 1u)) >> 16);
}

// LDS map (dynamic, 133120 B):
//   [0,65536)       cbh frags:  addr = T*4096 + s*1024 + h*512 + col*16
//   [65536,131072)  cbl frags:  same order, +65536
//   [131072,133120) nhc2 floats, arranged[t*32 + h*16 + r] = -0.5*c2(perm)

#define LDS_FRAGS(CH, CL, T) do { \
  const int fb_ = (T) * 4096 + h * 512 + col * 16; \
  CH[0] = *(const s16x8*)(smem + fb_); \
  CH[1] = *(const s16x8*)(smem + fb_ + 1024); \
  CH[2] = *(const s16x8*)(smem + fb_ + 2048); \
  CH[3] = *(const s16x8*)(smem + fb_ + 3072); \
  CL[0] = *(const s16x8*)(smem + 65536 + fb_); \
  CL[1] = *(const s16x8*)(smem + 65536 + fb_ + 1024); \
  CL[2] = *(const s16x8*)(smem + 65536 + fb_ + 2048); \
  CL[3] = *(const s16x8*)(smem + 65536 + fb_ + 3072); \
} while (0)

#define LDS_GG(G, T) do { \
  const int gb_ = 131072 + (((T) * 32 + h * 16) << 2); \
  G[0] = *(const float4*)(smem + gb_); \
  G[1] = *(const float4*)(smem + gb_ + 16); \
  G[2] = *(const float4*)(smem + gb_ + 32); \
  G[3] = *(const float4*)(smem + gb_ + 48); \
} while (0)

#define TILE_BODY(T, CH, CL, G) do { \
  f32x16 acc0, acc1 = {};            /* acc0 init = permuted -0.5*c2 (regs) */ \
  acc0[0]  = G[0].x; acc0[1]  = G[0].y; acc0[2]  = G[0].z; acc0[3]  = G[0].w; \
  acc0[4]  = G[1].x; acc0[5]  = G[1].y; acc0[6]  = G[1].z; acc0[7]  = G[1].w; \
  acc0[8]  = G[2].x; acc0[9]  = G[2].y; acc0[10] = G[2].z; acc0[11] = G[2].w; \
  acc0[12] = G[3].x; acc0[13] = G[3].y; acc0[14] = G[3].z; acc0[15] = G[3].w; \
  acc0 = MFMA_B(CH[0], zh[0], acc0);  acc1 = MFMA_B(CH[1], zh[1], acc1); \
  acc0 = MFMA_B(CH[2], zh[2], acc0);  acc1 = MFMA_B(CH[3], zh[3], acc1); \
  acc0 = MFMA_B(CH[0], zl[0], acc0);  acc1 = MFMA_B(CH[1], zl[1], acc1); \
  acc0 = MFMA_B(CH[2], zl[2], acc0);  acc1 = MFMA_B(CH[3], zl[3], acc1); \
  acc0 = MFMA_B(CL[0], zh[0], acc0);  acc1 = MFMA_B(CL[1], zh[1], acc1); \
  acc0 = MFMA_B(CL[2], zh[2], acc0);  acc1 = MFMA_B(CL[3], zh[3], acc1); \
  /* scan: two 8-chains + exact max/med merge (R8/R9-verified logic) */ \
  float m1a = -INFINITY, m2a = -INFINITY, m1b = -INFINITY, m2b = -INFINITY; \
  int ra_ = 0, rb_ = 8; \
  _Pragma("unroll") \
  for (int r = 0; r < 8; ++r) { \
    float v = acc0[r] + acc1[r];       /* s = dot - 0.5*c2 (c2 in acc0 init) */ \
    bool gt = v > m1a;                 /* strict: ties keep earliest */ \
    m2a = fminf(fmaxf(v, m2a), m1a);   /* med3: second-best (uses OLD m1) */ \
    if (gt) ra_ = r; \
    m1a = gt ? v : m1a; \
  } \
  _Pragma("unroll") \
  for (int r = 8; r < 16; ++r) { \
    float v = acc0[r] + acc1[r]; \
    bool gt = v > m1b; \
    m2b = fminf(fmaxf(v, m2b), m1b); \
    if (gt) rb_ = r; \
    m1b = gt ? v : m1b; \
  } \
  /* perm(r,h) monotone in r -> a-half holds the lower codewords */ \
  float tm1 = fmaxf(m1a, m1b); \
  float tm2 = fmaxf(fminf(m1a, m1b), fmaxf(m2a, m2b)); \
  int   tr_ = (m1b > m1a) ? rb_ : ra_;   /* strict: ties keep lower r */ \
  bool tgt = tm1 > m1;                   /* strict: ties keep earlier tile */ \
  m2 = fmaxf(fminf(tm1, m1), fmaxf(tm2, m2)); \
  if (tgt) { rbest = tr_; tbest = (T); } \
  m1 = tgt ? tm1 : m1; \
} while (0)

__global__ __launch_bounds__(512, 2)
void vq_main(const float* __restrict__ z, const float* __restrict__ cbk,
             float* __restrict__ out, float* __restrict__ lossAcc,
             unsigned* __restrict__ done, int N)
{
  extern __shared__ char smem[];

  const int tid  = threadIdx.x;
  const int lane = tid & 63;
  const int wave = tid >> 6;
  const int col  = lane & 31;    // this lane's z-row within the wave's 32 rows
  const int h    = lane >> 5;    // k-half / output split

  // ---- fill: convert codebook -> bf16 hi/lo frag-order tables + nhc2 ------
  // one thread = one codeword (512 threads, 512 codewords).
  {
    const int cw = tid;
    const float4* c4 = (const float4*)(cbk + (size_t)cw * D);
    float4 f[16];
    #pragma unroll
    for (int i = 0; i < D4; ++i) f[i] = c4[i];
    float c2 = 0.f;
    #pragma unroll
    for (int i = 0; i < D4; ++i) FMA4(c2, f[i], f[i]);
    float e[64];
    #pragma unroll
    for (int i = 0; i < D4; ++i) {
      e[4*i] = f[i].x; e[4*i+1] = f[i].y; e[4*i+2] = f[i].z; e[4*i+3] = f[i].w;
    }
    const int T = cw >> 5, cc = cw & 31;
    #pragma unroll
    for (int sl = 0; sl < 4; ++sl) {
      #pragma unroll
      for (int h2 = 0; h2 < 2; ++h2) {
        const int ld0 = sl * 16 + h2 * 8;
        s16x8 vh, vl;
        #pragma unroll
        for (int j = 0; j < 8; ++j) {
          unsigned short hb = f2bf(e[ld0 + j]);
          float hf = __uint_as_float((unsigned)hb << 16);
          vh[j] = (short)hb;
          vl[j] = (short)f2bf(e[ld0 + j] - hf);
        }
        const int a = T * 4096 + sl * 1024 + h2 * 512 + cc * 16;
        *(s16x8*)(smem + a) = vh;
        *(s16x8*)(smem + 65536 + a) = vl;
      }
    }
    // invert perm(r,h) = (r&3) + 8*(r>>2) + 4*h : arranged[t*32 + h*16 + r]
    const int ai = (T << 5) + (((cc >> 2) & 1) << 4) + ((cc >> 3) << 2) + (cc & 3);
    *(float*)(smem + 131072 + ai * 4) = -0.5f * c2;
  }
  __syncthreads();   // tables read-only afterwards: no more barriers

  float lacc = 0.f;

  #pragma unroll 1
  for (int it = 0; it < 4; ++it) {
    const long rowg = (long)blockIdx.x * 1024 + it * 256 + wave * 32 + col;

    // z row -> bf16 hi/lo B-frags. Lane holds k = 16s + 8h + j, j=0..7.
    const float4* zp4 = (const float4*)(z + (size_t)rowg * D);
    s16x8 zh[4], zl[4];
    #pragma unroll
    for (int s = 0; s < 4; ++s) {
      float4 p0 = zp4[4 * s + 2 * h];
      float4 p1 = zp4[4 * s + 2 * h + 1];
      float e[8] = {p0.x, p0.y, p0.z, p0.w, p1.x, p1.y, p1.z, p1.w};
      #pragma unroll
      for (int j = 0; j < 8; ++j) {
        unsigned short hb = f2bf(e[j]);
        float hf = __uint_as_float((unsigned)hb << 16);
        zh[s][j] = (short)hb;
        zl[s][j] = (short)f2bf(e[j] - hf);
      }
    }

    float m1 = -INFINITY, m2 = -INFINITY;
    int rbest = 0, tbest = 0;

    // 1-tile-ahead LDS prefetch, double reg set (R8-verified pipeline).
    s16x8 chA[4], clA[4], chB[4], clB[4];
    float4 gA[4], gB[4];
    LDS_FRAGS(chA, clA, 0);  LDS_GG(gA, 0);
    LDS_FRAGS(chB, clB, 1);  LDS_GG(gB, 1);
    #pragma unroll 1
    for (int t = 0; t < 14; t += 2) {
      TILE_BODY(t, chA, clA, gA);
      LDS_FRAGS(chA, clA, t + 2);  LDS_GG(gA, t + 2);
      TILE_BODY(t + 1, chB, clB, gB);
      LDS_FRAGS(chB, clB, t + 3);  LDS_GG(gB, t + 3);
    }
    TILE_BODY(14, chA, clA, gA);
    TILE_BODY(15, chB, clB, gB);

    // cw index from (tile, reg, half): perm(r,h) = (r&3) + 8*(r>>2) + 4h
    int idx = (tbest << 5) + (h << 2) + (rbest & 3) + ((rbest >> 2) << 3);

    // combine the two k-halves (lane <-> lane^32); lower cw wins ties
    float om1  = __shfl_xor(m1, 32);
    float om2  = __shfl_xor(m2, 32);
    int   oidx = __shfl_xor(idx, 32);
    float nm2 = fmaxf(fminf(m1, om1), fmaxf(m2, om2));
    bool take = (om1 > m1) || ((om1 == m1) && (oidx < idx));
    if (take) { m1 = om1; idx = oidx; }
    m2 = nm2;

    const bool certain = (m1 - m2 > STH);
    if (certain) {
      // provably the fp32 argmin. Epilogue ops identical to R4, split across
      // the lane pair (h picks the 32-element half of the row).
      const float4* qp = (const float4*)(cbk + (size_t)idx * D) + (h << 3);
      const float4* zp = (const float4*)(z + (size_t)rowg * D) + (h << 3);
      float4*       op = (float4*)(out + (size_t)rowg * D) + (h << 3);
      #pragma unroll
      for (int i = 0; i < 8; ++i) {
        float4 q = qp[i], zz = zp[i], u, qs;
        u.x = q.x - zz.x; u.y = q.y - zz.y; u.z = q.z - zz.z; u.w = q.w - zz.w;
        qs.x = zz.x + u.x; qs.y = zz.y + u.y; qs.z = zz.z + u.z; qs.w = zz.w + u.w;
        FMA4(lacc, u, u);
        op[i] = qs;
      }
      if (h == 0) (out + (size_t)N * D + 1)[rowg] = (float)idx;
    }

    // ---- inline exact fallback: wave cooperates on each uncertain col ----
    // Per-(row,k) chains BIT-IDENTICAL to R4/R7 (c2: FMA4 i=0..15 in order;
    // a0 = even chunks, b0 = odd chunks in order; d = fmaf(-2,dot,z2)+c2).
    // Cross-lane merge: min-d, tie -> lowest k == numpy first-min.
    unsigned mask32 = (unsigned)__ballot((!certain) && h == 0);
    while (mask32) {
      const int c = __builtin_ctz(mask32);
      mask32 &= mask32 - 1;
      const size_t r0 = (size_t)blockIdx.x * 1024 + it * 256 + wave * 32 + c;
      const float4* zp = (const float4*)(z + r0 * D);
      float4 z0[D4];
      #pragma unroll
      for (int i = 0; i < D4; ++i) z0[i] = zp[i];
      float z2 = 0.f;
      #pragma unroll
      for (int i = 0; i < D4; ++i) FMA4(z2, z0[i], z0[i]);

      float best = INFINITY;
      int   bi = 0;
      #pragma unroll 1
      for (int j = 0; j < 8; ++j) {
        const int k = (lane << 3) + j;
        const float4* c4 = (const float4*)(cbk + (size_t)k * D);
        float4 cr[D4];
        #pragma unroll
        for (int i = 0; i < D4; ++i) cr[i] = c4[i];
        float c2 = 0.f;
        #pragma unroll
        for (int i = 0; i < D4; ++i) FMA4(c2, cr[i], cr[i]);
        float a0 = 0.f, b0 = 0.f;
        #pragma unroll
        for (int i = 0; i < 8; ++i) {
          FMA4(a0, z0[2 * i],     cr[2 * i]);
          FMA4(b0, z0[2 * i + 1], cr[2 * i + 1]);
        }
        float dot = a0 + b0;
        float d = fmaf(-2.f, dot, z2) + c2;
        if (d < best) { best = d; bi = k; }   // strict <, ascending k
      }

      #pragma unroll
      for (int off = 32; off > 0; off >>= 1) {
        float ob = __shfl_xor(best, off, 64);
        int  obi = __shfl_xor(bi, off, 64);
        if (ob < best || (ob == best && obi < bi)) { best = ob; bi = obi; }
      }

      if (lane == 0) {
        const float4* qp = (const float4*)(cbk + (size_t)bi * D);
        float4* o = (float4*)(out + r0 * D);
        #pragma unroll
        for (int i = 0; i < D4; ++i) {
          float4 q = qp[i], zz = z0[i], u, qs;
          u.x = q.x - zz.x; u.y = q.y - zz.y; u.z = q.z - zz.z; u.w = q.w - zz.w;
          qs.x = zz.x + u.x; qs.y = zz.y + u.y; qs.z = zz.z + u.z; qs.w = zz.w + u.w;
          FMA4(lacc, u, u);
          o[i] = qs;
        }
        (out + (size_t)N * D + 1)[r0] = (float)bi;
      }
    }
  }

  // loss: wave shuffle reduce -> one atomicAdd per wave; last block finalizes.
  #pragma unroll
  for (int off = 32; off > 0; off >>= 1) lacc += __shfl_down(lacc, off, 64);
  if (lane == 0) atomicAdd(lossAcc, lacc);
  __syncthreads();
  if (tid == 0) {
    __threadfence();                               // publish this block's adds
    unsigned d = atomicAdd(done, 1u);
    if (d == gridDim.x - 1) {                      // last block: all adds done
      float total = atomicAdd(lossAcc, 0.0f);      // device-scope atomic read
      out[(size_t)N * D] = 1.25f * (total / (float)((long)N * D));
    }
  }
}

extern "C" void kernel_launch(void* const* d_in, const int* in_sizes, int n_in,
                              void* d_out, int out_size, void* d_ws, size_t ws_size,
                              hipStream_t stream)
{
  const float* z   = (const float*)d_in[0];
  const float* cbk = (const float*)d_in[1];
  float* out = (float*)d_out;
  float* ws  = (float*)d_ws;
  const int N = in_sizes[0] / D;

  // ws layout (floats): [0]=lossAcc, [1]=done counter
  float*    lossAcc = ws;
  unsigned* done    = (unsigned*)(ws + 1);

  hipMemsetAsync(ws, 0, 8, stream);  // clears lossAcc + done
  vq_main<<<N / 1024, 512, 133120, stream>>>(z, cbk, out, lossAcc, done, N);
}

// Round 7
// 224.180 us; speedup vs baseline: 1.0682x; 1.0066x over previous
//
#include <hip/hip_runtime.h>
#include <math.h>

// VQ quantizer: z [N,64] fp32, codebook [512,64] fp32.
// out layout (all fp32): q_ste [N*64] | loss [1] | ids-as-float [N]
//
// R1-R4: fp32-VALU ladder, 374us. R5: split-bf16 (hh+hl+lh) MFMA computes
// s = z.c - 0.5*|c|^2; rows with best-vs-runnerup margin > STH provably match
// the fp32 argmin; rest -> exact fallback. R8: 128KB LDS codebook staging,
// 512thr, double-buffered LDS prefetch: vq_mfma 96us + 118us outside (5
// dispatches). R9: fused to ONE kernel; fusion worked (gap->88) but VGPR
// cap 64 spilled. 239us. R10: R8 engine in R9 shell, launch_bounds(512,2):
// PASSED 225.7, vq_main 145us BUT VGPR_Count=128 with FETCH +54MB / WRITE
// +24MB vs R8 = hot-loop scratch spills (MfmaUtil 22.5->14.5): with extern
// __shared__ the compiler can't see the 133KB LDS, targeted 4 waves/SIMD
// (128 VGPR) and spilled z-frags reloaded every tile (262k rows x 16 tiles
// x 16B ~ the +54MB). R11 (this): tell the allocator the truth.
//  - amdgpu_waves_per_eu(2,2): occupancy IS 2 waves/EU (LDS-bound), so the
//    budget is 256 VGPR -> no spill. Single change targeting the spill.
//  - fallback codebook pass split into 2x8 float4 (R9-verified bit-identical
//    chains) to keep cold-path peak pressure under the budget.
//
// mfma_f32_32x32x16_bf16, A=codebook(M=32 cw), B=z(N=32 rows):
//   C/D: col=lane&31 (z-row), row=(reg&3)+8*(reg>>2)+4*(lane>>5) (codeword)
//   -> per-lane 16 accs are 16 codewords of the lane's OWN row.

constexpr int D     = 64;
constexpr int D4    = 16;      // float4s per row
constexpr int K     = 512;
constexpr float STH = 2e-4f;   // certainty margin in s-space (d-gap = 2*s-gap)

typedef __attribute__((ext_vector_type(8)))  short s16x8;
typedef __attribute__((ext_vector_type(16))) float f32x16;

#define FMA4(acc, zz, cc) do { \
  acc = fmaf((zz).x, (cc).x, acc); \
  acc = fmaf((zz).y, (cc).y, acc); \
  acc = fmaf((zz).z, (cc).z, acc); \
  acc = fmaf((zz).w, (cc).w, acc); } while (0)

#define MFMA_B(A, B, C) __builtin_amdgcn_mfma_f32_32x32x16_bf16(A, B, C, 0, 0, 0)

__device__ __forceinline__ unsigned short f2bf(float f) {
  unsigned u = __float_as_uint(f);
  return (unsigned short)((u + 0x7FFFu + ((u >> 16) & 1u)) >> 16);
}

// LDS map (dynamic, 133120 B):
//   [0,65536)       cbh frags:  addr = T*4096 + s*1024 + h*512 + col*16
//   [65536,131072)  cbl frags:  same order, +65536
//   [131072,133120) nhc2 floats, arranged[t*32 + h*16 + r] = -0.5*c2(perm)

#define LDS_FRAGS(CH, CL, T) do { \
  const int fb_ = (T) * 4096 + h * 512 + col * 16; \
  CH[0] = *(const s16x8*)(smem + fb_); \
  CH[1] = *(const s16x8*)(smem + fb_ + 1024); \
  CH[2] = *(const s16x8*)(smem + fb_ + 2048); \
  CH[3] = *(const s16x8*)(smem + fb_ + 3072); \
  CL[0] = *(const s16x8*)(smem + 65536 + fb_); \
  CL[1] = *(const s16x8*)(smem + 65536 + fb_ + 1024); \
  CL[2] = *(const s16x8*)(smem + 65536 + fb_ + 2048); \
  CL[3] = *(const s16x8*)(smem + 65536 + fb_ + 3072); \
} while (0)

#define LDS_GG(G, T) do { \
  const int gb_ = 131072 + (((T) * 32 + h * 16) << 2); \
  G[0] = *(const float4*)(smem + gb_); \
  G[1] = *(const float4*)(smem + gb_ + 16); \
  G[2] = *(const float4*)(smem + gb_ + 32); \
  G[3] = *(const float4*)(smem + gb_ + 48); \
} while (0)

#define TILE_BODY(T, CH, CL, G) do { \
  f32x16 acc0, acc1 = {};            /* acc0 init = permuted -0.5*c2 (regs) */ \
  acc0[0]  = G[0].x; acc0[1]  = G[0].y; acc0[2]  = G[0].z; acc0[3]  = G[0].w; \
  acc0[4]  = G[1].x; acc0[5]  = G[1].y; acc0[6]  = G[1].z; acc0[7]  = G[1].w; \
  acc0[8]  = G[2].x; acc0[9]  = G[2].y; acc0[10] = G[2].z; acc0[11] = G[2].w; \
  acc0[12] = G[3].x; acc0[13] = G[3].y; acc0[14] = G[3].z; acc0[15] = G[3].w; \
  acc0 = MFMA_B(CH[0], zh[0], acc0);  acc1 = MFMA_B(CH[1], zh[1], acc1); \
  acc0 = MFMA_B(CH[2], zh[2], acc0);  acc1 = MFMA_B(CH[3], zh[3], acc1); \
  acc0 = MFMA_B(CH[0], zl[0], acc0);  acc1 = MFMA_B(CH[1], zl[1], acc1); \
  acc0 = MFMA_B(CH[2], zl[2], acc0);  acc1 = MFMA_B(CH[3], zl[3], acc1); \
  acc0 = MFMA_B(CL[0], zh[0], acc0);  acc1 = MFMA_B(CL[1], zh[1], acc1); \
  acc0 = MFMA_B(CL[2], zh[2], acc0);  acc1 = MFMA_B(CL[3], zh[3], acc1); \
  /* scan: two 8-chains + exact max/med merge (R8/R9/R10-verified logic) */ \
  float m1a = -INFINITY, m2a = -INFINITY, m1b = -INFINITY, m2b = -INFINITY; \
  int ra_ = 0, rb_ = 8; \
  _Pragma("unroll") \
  for (int r = 0; r < 8; ++r) { \
    float v = acc0[r] + acc1[r];       /* s = dot - 0.5*c2 (c2 in acc0 init) */ \
    bool gt = v > m1a;                 /* strict: ties keep earliest */ \
    m2a = fminf(fmaxf(v, m2a), m1a);   /* med3: second-best (uses OLD m1) */ \
    if (gt) ra_ = r; \
    m1a = gt ? v : m1a; \
  } \
  _Pragma("unroll") \
  for (int r = 8; r < 16; ++r) { \
    float v = acc0[r] + acc1[r]; \
    bool gt = v > m1b; \
    m2b = fminf(fmaxf(v, m2b), m1b); \
    if (gt) rb_ = r; \
    m1b = gt ? v : m1b; \
  } \
  /* perm(r,h) monotone in r -> a-half holds the lower codewords */ \
  float tm1 = fmaxf(m1a, m1b); \
  float tm2 = fmaxf(fminf(m1a, m1b), fmaxf(m2a, m2b)); \
  int   tr_ = (m1b > m1a) ? rb_ : ra_;   /* strict: ties keep lower r */ \
  bool tgt = tm1 > m1;                   /* strict: ties keep earlier tile */ \
  m2 = fmaxf(fminf(tm1, m1), fmaxf(tm2, m2)); \
  if (tgt) { rbest = tr_; tbest = (T); } \
  m1 = tgt ? tm1 : m1; \
} while (0)

__global__ __launch_bounds__(512)
__attribute__((amdgpu_waves_per_eu(2, 2)))
void vq_main(const float* __restrict__ z, const float* __restrict__ cbk,
             float* __restrict__ out, float* __restrict__ lossAcc,
             unsigned* __restrict__ done, int N)
{
  extern __shared__ char smem[];

  const int tid  = threadIdx.x;
  const int lane = tid & 63;
  const int wave = tid >> 6;
  const int col  = lane & 31;    // this lane's z-row within the wave's 32 rows
  const int h    = lane >> 5;    // k-half / output split

  // ---- fill: convert codebook -> bf16 hi/lo frag-order tables + nhc2 ------
  // one thread = one codeword (512 threads, 512 codewords).
  {
    const int cw = tid;
    const float4* c4 = (const float4*)(cbk + (size_t)cw * D);
    float4 f[16];
    #pragma unroll
    for (int i = 0; i < D4; ++i) f[i] = c4[i];
    float c2 = 0.f;
    #pragma unroll
    for (int i = 0; i < D4; ++i) FMA4(c2, f[i], f[i]);
    float e[64];
    #pragma unroll
    for (int i = 0; i < D4; ++i) {
      e[4*i] = f[i].x; e[4*i+1] = f[i].y; e[4*i+2] = f[i].z; e[4*i+3] = f[i].w;
    }
    const int T = cw >> 5, cc = cw & 31;
    #pragma unroll
    for (int sl = 0; sl < 4; ++sl) {
      #pragma unroll
      for (int h2 = 0; h2 < 2; ++h2) {
        const int ld0 = sl * 16 + h2 * 8;
        s16x8 vh, vl;
        #pragma unroll
        for (int j = 0; j < 8; ++j) {
          unsigned short hb = f2bf(e[ld0 + j]);
          float hf = __uint_as_float((unsigned)hb << 16);
          vh[j] = (short)hb;
          vl[j] = (short)f2bf(e[ld0 + j] - hf);
        }
        const int a = T * 4096 + sl * 1024 + h2 * 512 + cc * 16;
        *(s16x8*)(smem + a) = vh;
        *(s16x8*)(smem + 65536 + a) = vl;
      }
    }
    // invert perm(r,h) = (r&3) + 8*(r>>2) + 4*h : arranged[t*32 + h*16 + r]
    const int ai = (T << 5) + (((cc >> 2) & 1) << 4) + ((cc >> 3) << 2) + (cc & 3);
    *(float*)(smem + 131072 + ai * 4) = -0.5f * c2;
  }
  __syncthreads();   // tables read-only afterwards: no more barriers

  float lacc = 0.f;

  #pragma unroll 1
  for (int it = 0; it < 4; ++it) {
    const long rowg = (long)blockIdx.x * 1024 + it * 256 + wave * 32 + col;

    // z row -> bf16 hi/lo B-frags. Lane holds k = 16s + 8h + j, j=0..7.
    const float4* zp4 = (const float4*)(z + (size_t)rowg * D);
    s16x8 zh[4], zl[4];
    #pragma unroll
    for (int s = 0; s < 4; ++s) {
      float4 p0 = zp4[4 * s + 2 * h];
      float4 p1 = zp4[4 * s + 2 * h + 1];
      float e[8] = {p0.x, p0.y, p0.z, p0.w, p1.x, p1.y, p1.z, p1.w};
      #pragma unroll
      for (int j = 0; j < 8; ++j) {
        unsigned short hb = f2bf(e[j]);
        float hf = __uint_as_float((unsigned)hb << 16);
        zh[s][j] = (short)hb;
        zl[s][j] = (short)f2bf(e[j] - hf);
      }
    }

    float m1 = -INFINITY, m2 = -INFINITY;
    int rbest = 0, tbest = 0;

    // 1-tile-ahead LDS prefetch, double reg set (R8-verified pipeline).
    s16x8 chA[4], clA[4], chB[4], clB[4];
    float4 gA[4], gB[4];
    LDS_FRAGS(chA, clA, 0);  LDS_GG(gA, 0);
    LDS_FRAGS(chB, clB, 1);  LDS_GG(gB, 1);
    #pragma unroll 1
    for (int t = 0; t < 14; t += 2) {
      TILE_BODY(t, chA, clA, gA);
      LDS_FRAGS(chA, clA, t + 2);  LDS_GG(gA, t + 2);
      TILE_BODY(t + 1, chB, clB, gB);
      LDS_FRAGS(chB, clB, t + 3);  LDS_GG(gB, t + 3);
    }
    TILE_BODY(14, chA, clA, gA);
    TILE_BODY(15, chB, clB, gB);

    // cw index from (tile, reg, half): perm(r,h) = (r&3) + 8*(r>>2) + 4h
    int idx = (tbest << 5) + (h << 2) + (rbest & 3) + ((rbest >> 2) << 3);

    // combine the two k-halves (lane <-> lane^32); lower cw wins ties
    float om1  = __shfl_xor(m1, 32);
    float om2  = __shfl_xor(m2, 32);
    int   oidx = __shfl_xor(idx, 32);
    float nm2 = fmaxf(fminf(m1, om1), fmaxf(m2, om2));
    bool take = (om1 > m1) || ((om1 == m1) && (oidx < idx));
    if (take) { m1 = om1; idx = oidx; }
    m2 = nm2;

    const bool certain = (m1 - m2 > STH);
    if (certain) {
      // provably the fp32 argmin. Epilogue ops identical to R4, split across
      // the lane pair (h picks the 32-element half of the row).
      const float4* qp = (const float4*)(cbk + (size_t)idx * D) + (h << 3);
      const float4* zp = (const float4*)(z + (size_t)rowg * D) + (h << 3);
      float4*       op = (float4*)(out + (size_t)rowg * D) + (h << 3);
      #pragma unroll
      for (int i = 0; i < 8; ++i) {
        float4 q = qp[i], zz = zp[i], u, qs;
        u.x = q.x - zz.x; u.y = q.y - zz.y; u.z = q.z - zz.z; u.w = q.w - zz.w;
        qs.x = zz.x + u.x; qs.y = zz.y + u.y; qs.z = zz.z + u.z; qs.w = zz.w + u.w;
        FMA4(lacc, u, u);
        op[i] = qs;
      }
      if (h == 0) (out + (size_t)N * D + 1)[rowg] = (float)idx;
    }

    // ---- inline exact fallback: wave cooperates on each uncertain col ----
    // Per-(row,k) chains BIT-IDENTICAL to R4/R7 (c2: FMA4 i=0..15 in order;
    // a0 = even chunks, b0 = odd chunks in order; d = fmaf(-2,dot,z2)+c2).
    // Two-pass cr[8] (R9-verified) keeps cold-path peak VGPR pressure low.
    // Cross-lane merge: min-d, tie -> lowest k == numpy first-min.
    unsigned mask32 = (unsigned)__ballot((!certain) && h == 0);
    while (mask32) {
      const int c = __builtin_ctz(mask32);
      mask32 &= mask32 - 1;
      const size_t r0 = (size_t)blockIdx.x * 1024 + it * 256 + wave * 32 + c;
      const float4* zp = (const float4*)(z + r0 * D);
      float4 z0[D4];
      #pragma unroll
      for (int i = 0; i < D4; ++i) z0[i] = zp[i];
      float z2 = 0.f;
      #pragma unroll
      for (int i = 0; i < D4; ++i) FMA4(z2, z0[i], z0[i]);

      float best = INFINITY;
      int   bi = 0;
      #pragma unroll 1
      for (int j = 0; j < 8; ++j) {
        const int k = (lane << 3) + j;
        const float4* c4 = (const float4*)(cbk + (size_t)k * D);
        float c2 = 0.f, a0 = 0.f, b0 = 0.f;
        float4 cr[8];
        #pragma unroll
        for (int i = 0; i < 8; ++i) cr[i] = c4[i];
        #pragma unroll
        for (int i = 0; i < 8; ++i) FMA4(c2, cr[i], cr[i]);
        #pragma unroll
        for (int i = 0; i < 4; ++i) {
          FMA4(a0, z0[2 * i],     cr[2 * i]);
          FMA4(b0, z0[2 * i + 1], cr[2 * i + 1]);
        }
        #pragma unroll
        for (int i = 0; i < 8; ++i) cr[i] = c4[8 + i];
        #pragma unroll
        for (int i = 0; i < 8; ++i) FMA4(c2, cr[i], cr[i]);
        #pragma unroll
        for (int i = 0; i < 4; ++i) {
          FMA4(a0, z0[8 + 2 * i], cr[2 * i]);
          FMA4(b0, z0[9 + 2 * i], cr[2 * i + 1]);
        }
        float dot = a0 + b0;
        float d = fmaf(-2.f, dot, z2) + c2;
        if (d < best) { best = d; bi = k; }   // strict <, ascending k
      }

      #pragma unroll
      for (int off = 32; off > 0; off >>= 1) {
        float ob = __shfl_xor(best, off, 64);
        int  obi = __shfl_xor(bi, off, 64);
        if (ob < best || (ob == best && obi < bi)) { best = ob; bi = obi; }
      }

      if (lane == 0) {
        const float4* qp = (const float4*)(cbk + (size_t)bi * D);
        float4* o = (float4*)(out + r0 * D);
        #pragma unroll
        for (int i = 0; i < D4; ++i) {
          float4 q = qp[i], zz = z0[i], u, qs;
          u.x = q.x - zz.x; u.y = q.y - zz.y; u.z = q.z - zz.z; u.w = q.w - zz.w;
          qs.x = zz.x + u.x; qs.y = zz.y + u.y; qs.z = zz.z + u.z; qs.w = zz.w + u.w;
          FMA4(lacc, u, u);
          o[i] = qs;
        }
        (out + (size_t)N * D + 1)[r0] = (float)bi;
      }
    }
  }

  // loss: wave shuffle reduce -> one atomicAdd per wave; last block finalizes.
  #pragma unroll
  for (int off = 32; off > 0; off >>= 1) lacc += __shfl_down(lacc, off, 64);
  if (lane == 0) atomicAdd(lossAcc, lacc);
  __syncthreads();
  if (tid == 0) {
    __threadfence();                               // publish this block's adds
    unsigned d = atomicAdd(done, 1u);
    if (d == gridDim.x - 1) {                      // last block: all adds done
      float total = atomicAdd(lossAcc, 0.0f);      // device-scope atomic read
      out[(size_t)N * D] = 1.25f * (total / (float)((long)N * D));
    }
  }
}

extern "C" void kernel_launch(void* const* d_in, const int* in_sizes, int n_in,
                              void* d_out, int out_size, void* d_ws, size_t ws_size,
                              hipStream_t stream)
{
  const float* z   = (const float*)d_in[0];
  const float* cbk = (const float*)d_in[1];
  float* out = (float*)d_out;
  float* ws  = (float*)d_ws;
  const int N = in_sizes[0] / D;

  // ws layout (floats): [0]=lossAcc, [1]=done counter
  float*    lossAcc = ws;
  unsigned* done    = (unsigned*)(ws + 1);

  hipMemsetAsync(ws, 0, 8, stream);  // clears lossAcc + done
  vq_main<<<N / 1024, 512, 133120, stream>>>(z, cbk, out, lossAcc, done, N);
}

// Round 8
// 218.920 us; speedup vs baseline: 1.0938x; 1.0240x over previous
//
#include <hip/hip_runtime.h>
#include <math.h>

// VQ quantizer: z [N,64] fp32, codebook [512,64] fp32.
// out layout (all fp32): q_ste [N*64] | loss [1] | ids-as-float [N]
//
// R5: split-bf16 (hh+hl+lh) MFMA computes s = z.c - 0.5*|c|^2; rows with
// best-vs-runnerup margin > STH provably match the fp32 argmin; rest get an
// exact fp32 fallback. R8 (5 dispatches): 128KB LDS codebook staging + 1-tile
// -ahead double-buffered prefetch -> engine 96us @ VGPR 112, MfmaUtil 22.5.
// R9-R11 (fused single kernel): dispatch overhead shrank BUT the fused
// kernel's cold paths (fallback z0[16]+cr[8] ~96 VGPR, fill arrays) poison
// the global register allocation: VGPR pinned at 128 with ~77MB of scratch
// traffic (FETCH +53MB, WRITE +24MB vs R8) and MfmaUtil 14.5 -> engine 145us.
// launch_bounds(512,2) [R10] and amdgpu_waves_per_eu(2,2) [R11] both failed
// to move the allocator. R12 (this): separate the allocation domains again.
//  - Kernel A = R10 minus inline-fallback minus finalize: in-block codebook
//    conversion fill, frag-order LDS (0 conflicts), double-buffered LDS
//    prefetch, scan, certain-path epilogue, flag list via atomicAdd.
//    Structurally identical hot loop to R8's 96us/112-VGPR engine.
//  - Kernel B = R6/R7-verified wave-per-row exact fallback (chains
//    BIT-IDENTICAL to R4; first-min merge) + loss finalize via done-counter
//    among B's blocks (A's lossAcc adds visible by stream order).
//  - 3 dispatches: 12B memset + A + B.
//
// mfma_f32_32x32x16_bf16, A=codebook(M=32 cw), B=z(N=32 rows):
//   C/D: col=lane&31 (z-row), row=(reg&3)+8*(reg>>2)+4*(lane>>5) (codeword)
//   -> per-lane 16 accs are 16 codewords of the lane's OWN row.

constexpr int D     = 64;
constexpr int D4    = 16;      // float4s per row
constexpr int K     = 512;
constexpr float STH = 2e-4f;   // certainty margin in s-space (d-gap = 2*s-gap)

typedef __attribute__((ext_vector_type(8)))  short s16x8;
typedef __attribute__((ext_vector_type(16))) float f32x16;

#define FMA4(acc, zz, cc) do { \
  acc = fmaf((zz).x, (cc).x, acc); \
  acc = fmaf((zz).y, (cc).y, acc); \
  acc = fmaf((zz).z, (cc).z, acc); \
  acc = fmaf((zz).w, (cc).w, acc); } while (0)

#define MFMA_B(A, B, C) __builtin_amdgcn_mfma_f32_32x32x16_bf16(A, B, C, 0, 0, 0)

__device__ __forceinline__ unsigned short f2bf(float f) {
  unsigned u = __float_as_uint(f);
  return (unsigned short)((u + 0x7FFFu + ((u >> 16) & 1u)) >> 16);
}

// LDS map (dynamic, 133120 B):
//   [0,65536)       cbh frags:  addr = T*4096 + s*1024 + h*512 + col*16
//   [65536,131072)  cbl frags:  same order, +65536
//   [131072,133120) nhc2 floats, arranged[t*32 + h*16 + r] = -0.5*c2(perm)

#define LDS_FRAGS(CH, CL, T) do { \
  const int fb_ = (T) * 4096 + h * 512 + col * 16; \
  CH[0] = *(const s16x8*)(smem + fb_); \
  CH[1] = *(const s16x8*)(smem + fb_ + 1024); \
  CH[2] = *(const s16x8*)(smem + fb_ + 2048); \
  CH[3] = *(const s16x8*)(smem + fb_ + 3072); \
  CL[0] = *(const s16x8*)(smem + 65536 + fb_); \
  CL[1] = *(const s16x8*)(smem + 65536 + fb_ + 1024); \
  CL[2] = *(const s16x8*)(smem + 65536 + fb_ + 2048); \
  CL[3] = *(const s16x8*)(smem + 65536 + fb_ + 3072); \
} while (0)

#define LDS_GG(G, T) do { \
  const int gb_ = 131072 + (((T) * 32 + h * 16) << 2); \
  G[0] = *(const float4*)(smem + gb_); \
  G[1] = *(const float4*)(smem + gb_ + 16); \
  G[2] = *(const float4*)(smem + gb_ + 32); \
  G[3] = *(const float4*)(smem + gb_ + 48); \
} while (0)

#define TILE_BODY(T, CH, CL, G) do { \
  f32x16 acc0, acc1 = {};            /* acc0 init = permuted -0.5*c2 (regs) */ \
  acc0[0]  = G[0].x; acc0[1]  = G[0].y; acc0[2]  = G[0].z; acc0[3]  = G[0].w; \
  acc0[4]  = G[1].x; acc0[5]  = G[1].y; acc0[6]  = G[1].z; acc0[7]  = G[1].w; \
  acc0[8]  = G[2].x; acc0[9]  = G[2].y; acc0[10] = G[2].z; acc0[11] = G[2].w; \
  acc0[12] = G[3].x; acc0[13] = G[3].y; acc0[14] = G[3].z; acc0[15] = G[3].w; \
  acc0 = MFMA_B(CH[0], zh[0], acc0);  acc1 = MFMA_B(CH[1], zh[1], acc1); \
  acc0 = MFMA_B(CH[2], zh[2], acc0);  acc1 = MFMA_B(CH[3], zh[3], acc1); \
  acc0 = MFMA_B(CH[0], zl[0], acc0);  acc1 = MFMA_B(CH[1], zl[1], acc1); \
  acc0 = MFMA_B(CH[2], zl[2], acc0);  acc1 = MFMA_B(CH[3], zl[3], acc1); \
  acc0 = MFMA_B(CL[0], zh[0], acc0);  acc1 = MFMA_B(CL[1], zh[1], acc1); \
  acc0 = MFMA_B(CL[2], zh[2], acc0);  acc1 = MFMA_B(CL[3], zh[3], acc1); \
  /* scan: two 8-chains + exact max/med merge (R8-R11 verified logic) */ \
  float m1a = -INFINITY, m2a = -INFINITY, m1b = -INFINITY, m2b = -INFINITY; \
  int ra_ = 0, rb_ = 8; \
  _Pragma("unroll") \
  for (int r = 0; r < 8; ++r) { \
    float v = acc0[r] + acc1[r];       /* s = dot - 0.5*c2 (c2 in acc0 init) */ \
    bool gt = v > m1a;                 /* strict: ties keep earliest */ \
    m2a = fminf(fmaxf(v, m2a), m1a);   /* med3: second-best (uses OLD m1) */ \
    if (gt) ra_ = r; \
    m1a = gt ? v : m1a; \
  } \
  _Pragma("unroll") \
  for (int r = 8; r < 16; ++r) { \
    float v = acc0[r] + acc1[r]; \
    bool gt = v > m1b; \
    m2b = fminf(fmaxf(v, m2b), m1b); \
    if (gt) rb_ = r; \
    m1b = gt ? v : m1b; \
  } \
  /* perm(r,h) monotone in r -> a-half holds the lower codewords */ \
  float tm1 = fmaxf(m1a, m1b); \
  float tm2 = fmaxf(fminf(m1a, m1b), fmaxf(m2a, m2b)); \
  int   tr_ = (m1b > m1a) ? rb_ : ra_;   /* strict: ties keep lower r */ \
  bool tgt = tm1 > m1;                   /* strict: ties keep earlier tile */ \
  m2 = fmaxf(fminf(tm1, m1), fmaxf(tm2, m2)); \
  if (tgt) { rbest = tr_; tbest = (T); } \
  m1 = tgt ? tm1 : m1; \
} while (0)

__global__ __launch_bounds__(512)
void vq_main(const float* __restrict__ z, const float* __restrict__ cbk,
             float* __restrict__ out, float* __restrict__ lossAcc,
             unsigned* __restrict__ cnt, unsigned* __restrict__ list, int N)
{
  extern __shared__ char smem[];

  const int tid  = threadIdx.x;
  const int lane = tid & 63;
  const int wave = tid >> 6;
  const int col  = lane & 31;    // this lane's z-row within the wave's 32 rows
  const int h    = lane >> 5;    // k-half / output split

  // ---- fill: convert codebook -> bf16 hi/lo frag-order tables + nhc2 ------
  // one thread = one codeword (512 threads, 512 codewords). R10-verified.
  {
    const int cw = tid;
    const float4* c4 = (const float4*)(cbk + (size_t)cw * D);
    float4 f[16];
    #pragma unroll
    for (int i = 0; i < D4; ++i) f[i] = c4[i];
    float c2 = 0.f;
    #pragma unroll
    for (int i = 0; i < D4; ++i) FMA4(c2, f[i], f[i]);
    float e[64];
    #pragma unroll
    for (int i = 0; i < D4; ++i) {
      e[4*i] = f[i].x; e[4*i+1] = f[i].y; e[4*i+2] = f[i].z; e[4*i+3] = f[i].w;
    }
    const int T = cw >> 5, cc = cw & 31;
    #pragma unroll
    for (int sl = 0; sl < 4; ++sl) {
      #pragma unroll
      for (int h2 = 0; h2 < 2; ++h2) {
        const int ld0 = sl * 16 + h2 * 8;
        s16x8 vh, vl;
        #pragma unroll
        for (int j = 0; j < 8; ++j) {
          unsigned short hb = f2bf(e[ld0 + j]);
          float hf = __uint_as_float((unsigned)hb << 16);
          vh[j] = (short)hb;
          vl[j] = (short)f2bf(e[ld0 + j] - hf);
        }
        const int a = T * 4096 + sl * 1024 + h2 * 512 + cc * 16;
        *(s16x8*)(smem + a) = vh;
        *(s16x8*)(smem + 65536 + a) = vl;
      }
    }
    // invert perm(r,h) = (r&3) + 8*(r>>2) + 4*h : arranged[t*32 + h*16 + r]
    const int ai = (T << 5) + (((cc >> 2) & 1) << 4) + ((cc >> 3) << 2) + (cc & 3);
    *(float*)(smem + 131072 + ai * 4) = -0.5f * c2;
  }
  __syncthreads();   // tables read-only afterwards: no more barriers

  float lacc = 0.f;

  #pragma unroll 1
  for (int it = 0; it < 4; ++it) {
    const long rowg = (long)blockIdx.x * 1024 + it * 256 + wave * 32 + col;

    // z row -> bf16 hi/lo B-frags. Lane holds k = 16s + 8h + j, j=0..7.
    const float4* zp4 = (const float4*)(z + (size_t)rowg * D);
    s16x8 zh[4], zl[4];
    #pragma unroll
    for (int s = 0; s < 4; ++s) {
      float4 p0 = zp4[4 * s + 2 * h];
      float4 p1 = zp4[4 * s + 2 * h + 1];
      float e[8] = {p0.x, p0.y, p0.z, p0.w, p1.x, p1.y, p1.z, p1.w};
      #pragma unroll
      for (int j = 0; j < 8; ++j) {
        unsigned short hb = f2bf(e[j]);
        float hf = __uint_as_float((unsigned)hb << 16);
        zh[s][j] = (short)hb;
        zl[s][j] = (short)f2bf(e[j] - hf);
      }
    }

    float m1 = -INFINITY, m2 = -INFINITY;
    int rbest = 0, tbest = 0;

    // 1-tile-ahead LDS prefetch, double reg set (R8-verified pipeline).
    s16x8 chA[4], clA[4], chB[4], clB[4];
    float4 gA[4], gB[4];
    LDS_FRAGS(chA, clA, 0);  LDS_GG(gA, 0);
    LDS_FRAGS(chB, clB, 1);  LDS_GG(gB, 1);
    #pragma unroll 1
    for (int t = 0; t < 14; t += 2) {
      TILE_BODY(t, chA, clA, gA);
      LDS_FRAGS(chA, clA, t + 2);  LDS_GG(gA, t + 2);
      TILE_BODY(t + 1, chB, clB, gB);
      LDS_FRAGS(chB, clB, t + 3);  LDS_GG(gB, t + 3);
    }
    TILE_BODY(14, chA, clA, gA);
    TILE_BODY(15, chB, clB, gB);

    // cw index from (tile, reg, half): perm(r,h) = (r&3) + 8*(r>>2) + 4h
    int idx = (tbest << 5) + (h << 2) + (rbest & 3) + ((rbest >> 2) << 3);

    // combine the two k-halves (lane <-> lane^32); lower cw wins ties
    float om1  = __shfl_xor(m1, 32);
    float om2  = __shfl_xor(m2, 32);
    int   oidx = __shfl_xor(idx, 32);
    float nm2 = fmaxf(fminf(m1, om1), fmaxf(m2, om2));
    bool take = (om1 > m1) || ((om1 == m1) && (oidx < idx));
    if (take) { m1 = om1; idx = oidx; }
    m2 = nm2;

    if (m1 - m2 > STH) {
      // certain: provably the fp32 argmin. Epilogue ops identical to R4,
      // split across the lane pair (h picks the 32-element half of the row).
      const float4* qp = (const float4*)(cbk + (size_t)idx * D) + (h << 3);
      const float4* zp = (const float4*)(z + (size_t)rowg * D) + (h << 3);
      float4*       op = (float4*)(out + (size_t)rowg * D) + (h << 3);
      #pragma unroll
      for (int i = 0; i < 8; ++i) {
        float4 q = qp[i], zz = zp[i], u, qs;
        u.x = q.x - zz.x; u.y = q.y - zz.y; u.z = q.z - zz.z; u.w = q.w - zz.w;
        qs.x = zz.x + u.x; qs.y = zz.y + u.y; qs.z = zz.z + u.z; qs.w = zz.w + u.w;
        FMA4(lacc, u, u);
        op[i] = qs;
      }
      if (h == 0) (out + (size_t)N * D + 1)[rowg] = (float)idx;
    } else if (h == 0) {
      unsigned p = atomicAdd(cnt, 1u);     // flagged -> exact fallback kernel
      list[p] = (unsigned)rowg;
    }
  }

  // loss (certain rows): wave shuffle reduce -> one atomicAdd per wave.
  #pragma unroll
  for (int off = 32; off > 0; off >>= 1) lacc += __shfl_down(lacc, off, 64);
  if (lane == 0) atomicAdd(lossAcc, lacc);
}

// ---------------- fallback + finalize: wave-per-row exact R4 chains ---------
// Lane handles 8 consecutive codewords (k = lane*8+j); per-(row,k) the FMA
// chains are BIT-IDENTICAL to R4/R7 (c2: FMA4 over 16 float4s in order; dot:
// a0=even chunks / b0=odd chunks in order; d = fmaf(-2,dot,z2)+c2).
// Cross-lane merge keeps min-d, tie -> lowest k == numpy first-min.
// Loss finalized by the last B-block (A's adds visible by stream order).
__global__ __launch_bounds__(256)
void vq_fb(const float* __restrict__ z, const float* __restrict__ cbk,
           float* __restrict__ out, float* __restrict__ lossAcc,
           const unsigned* __restrict__ list, const unsigned* __restrict__ cntp,
           unsigned* __restrict__ done, int N)
{
  const unsigned cnt = *cntp;
  const int tid  = threadIdx.x;
  const int lane = tid & 63;
  const unsigned wid = (blockIdx.x * blockDim.x + tid) >> 6;
  const unsigned nw  = (gridDim.x * blockDim.x) >> 6;

  float lacc = 0.f;
  #pragma unroll 1
  for (unsigned p = wid; p < cnt; p += nw) {
    const size_t r0 = (size_t)list[p];

    const float4* zp = (const float4*)(z + r0 * D);
    float4 z0[D4];
    #pragma unroll
    for (int i = 0; i < D4; ++i) z0[i] = zp[i];
    float z2 = 0.f;
    #pragma unroll
    for (int i = 0; i < D4; ++i) FMA4(z2, z0[i], z0[i]);

    float best = INFINITY;
    int   bi = 0;
    #pragma unroll 1
    for (int j = 0; j < 8; ++j) {
      const int k = (lane << 3) + j;
      const float4* c4 = (const float4*)(cbk + (size_t)k * D);
      float4 cr[D4];
      #pragma unroll
      for (int i = 0; i < D4; ++i) cr[i] = c4[i];
      float c2 = 0.f;
      #pragma unroll
      for (int i = 0; i < D4; ++i) FMA4(c2, cr[i], cr[i]);
      float a0 = 0.f, b0 = 0.f;
      #pragma unroll
      for (int i = 0; i < 8; ++i) {
        FMA4(a0, z0[2 * i],     cr[2 * i]);
        FMA4(b0, z0[2 * i + 1], cr[2 * i + 1]);
      }
      float dot = a0 + b0;
      float d = fmaf(-2.f, dot, z2) + c2;
      if (d < best) { best = d; bi = k; }   // strict <, ascending k
    }

    #pragma unroll
    for (int off = 32; off > 0; off >>= 1) {
      float ob = __shfl_xor(best, off, 64);
      int  obi = __shfl_xor(bi, off, 64);
      if (ob < best || (ob == best && obi < bi)) { best = ob; bi = obi; }
    }

    if (lane == 0) {
      const float4* qp = (const float4*)(cbk + (size_t)bi * D);
      float4* o = (float4*)(out + r0 * D);
      #pragma unroll
      for (int i = 0; i < D4; ++i) {
        float4 q = qp[i], zz = z0[i], u, qs;
        u.x = q.x - zz.x; u.y = q.y - zz.y; u.z = q.z - zz.z; u.w = q.w - zz.w;
        qs.x = zz.x + u.x; qs.y = zz.y + u.y; qs.z = zz.z + u.z; qs.w = zz.w + u.w;
        FMA4(lacc, u, u);
        o[i] = qs;
      }
      (out + (size_t)N * D + 1)[r0] = (float)bi;
    }
  }

  // add this kernel's loss contributions, then last block finalizes
  #pragma unroll
  for (int off = 32; off > 0; off >>= 1) lacc += __shfl_down(lacc, off, 64);
  __shared__ float wsum[4];
  if (lane == 0) wsum[tid >> 6] = lacc;
  __syncthreads();
  if (tid == 0) {
    float s = wsum[0] + wsum[1] + wsum[2] + wsum[3];
    if (s != 0.f) atomicAdd(lossAcc, s);
    __threadfence();                               // publish before done-add
    unsigned d = atomicAdd(done, 1u);
    if (d == gridDim.x - 1) {                      // last block: all adds done
      float total = atomicAdd(lossAcc, 0.0f);      // device-scope atomic read
      out[(size_t)N * D] = 1.25f * (total / (float)((long)N * D));
    }
  }
}

extern "C" void kernel_launch(void* const* d_in, const int* in_sizes, int n_in,
                              void* d_out, int out_size, void* d_ws, size_t ws_size,
                              hipStream_t stream)
{
  const float* z   = (const float*)d_in[0];
  const float* cbk = (const float*)d_in[1];
  float* out = (float*)d_out;
  float* ws  = (float*)d_ws;
  const int N = in_sizes[0] / D;

  // ws layout (floats): [0]=lossAcc, [1]=flagCount, [2]=done, [64..)=flag list
  float*    lossAcc = ws;
  unsigned* cnt     = (unsigned*)(ws + 1);
  unsigned* done    = (unsigned*)(ws + 2);
  unsigned* list    = (unsigned*)(ws + 64);

  hipMemsetAsync(ws, 0, 12, stream);  // clears lossAcc + flagCount + done
  vq_main<<<N / 1024, 512, 133120, stream>>>(z, cbk, out, lossAcc, cnt, list, N);
  vq_fb<<<512, 256, 0, stream>>>(z, cbk, out, lossAcc, list, cnt, done, N);
}

// Round 9
// 214.268 us; speedup vs baseline: 1.1176x; 1.0217x over previous
//
#include <hip/hip_runtime.h>
#include <math.h>

// VQ quantizer: z [N,64] fp32, codebook [512,64] fp32.
// out layout (all fp32): q_ste [N*64] | loss [1] | ids-as-float [N]
//
// R5: split-bf16 (hh+hl+lh) MFMA computes s = z.c - 0.5*|c|^2; rows with
// best-vs-runnerup margin > STH provably match the fp32 argmin; rest get an
// exact fp32 fallback. R8: 128KB LDS staging + double-buffered prefetch ->
// engine 96us. R9-R11: fusion experiments — cold paths poisoned regalloc
// (VGPR pin 128 + scratch). R12: 3-dispatch split (A=engine+fill, B=exact
// fallback+finalize): vq_main 108us, MfmaUtil 19, VALUBusy 36.5, but FETCH
// 94.6/WRITE 84 MB (~44MB surplus = fill's f[16]+e[64] spilling: 512thr x
// 256blk x ~170B) and the scan still costs 5-6 VALU/value at 55% issue util.
// R13 (this):
//  (a) chunked fill (16 elems/chunk, same c2 FMA order -> bit-identical,
//      peak live ~30 regs) -> no fill spill;
//  (b) index-embedded exact top-2 scan: v' = (bits(v)&~15)|(15-r) [1 ulp-
//      level perturbation, absorbed by STH; sub-ulp ties are flagged ->
//      fallback resolves exactly], then per pair t=med3(va,vb,m1);
//      m1=max3(va,vb,m1); m2=max(m2,t)  == exact streaming top-2.
//      rbest = 15-(bits(m1)&15) free; tbest = bit-compare per tile.
//      ~58 VALU/tile vs ~86.
//
// mfma_f32_32x32x16_bf16, A=codebook(M=32 cw), B=z(N=32 rows):
//   C/D: col=lane&31 (z-row), row=(reg&3)+8*(reg>>2)+4*(lane>>5) (codeword)
//   -> per-lane 16 accs are 16 codewords of the lane's OWN row.

constexpr int D     = 64;
constexpr int D4    = 16;      // float4s per row
constexpr int K     = 512;
constexpr float STH = 2e-4f;   // certainty margin in s-space (d-gap = 2*s-gap)

typedef __attribute__((ext_vector_type(8)))  short s16x8;
typedef __attribute__((ext_vector_type(16))) float f32x16;

#define FMA4(acc, zz, cc) do { \
  acc = fmaf((zz).x, (cc).x, acc); \
  acc = fmaf((zz).y, (cc).y, acc); \
  acc = fmaf((zz).z, (cc).z, acc); \
  acc = fmaf((zz).w, (cc).w, acc); } while (0)

#define MFMA_B(A, B, C) __builtin_amdgcn_mfma_f32_32x32x16_bf16(A, B, C, 0, 0, 0)

__device__ __forceinline__ unsigned short f2bf(float f) {
  unsigned u = __float_as_uint(f);
  return (unsigned short)((u + 0x7FFFu + ((u >> 16) & 1u)) >> 16);
}

// LDS map (dynamic, 133120 B):
//   [0,65536)       cbh frags:  addr = T*4096 + s*1024 + h*512 + col*16
//   [65536,131072)  cbl frags:  same order, +65536
//   [131072,133120) nhc2 floats, arranged[t*32 + h*16 + r] = -0.5*c2(perm)

#define LDS_FRAGS(CH, CL, T) do { \
  const int fb_ = (T) * 4096 + h * 512 + col * 16; \
  CH[0] = *(const s16x8*)(smem + fb_); \
  CH[1] = *(const s16x8*)(smem + fb_ + 1024); \
  CH[2] = *(const s16x8*)(smem + fb_ + 2048); \
  CH[3] = *(const s16x8*)(smem + fb_ + 3072); \
  CL[0] = *(const s16x8*)(smem + 65536 + fb_); \
  CL[1] = *(const s16x8*)(smem + 65536 + fb_ + 1024); \
  CL[2] = *(const s16x8*)(smem + 65536 + fb_ + 2048); \
  CL[3] = *(const s16x8*)(smem + 65536 + fb_ + 3072); \
} while (0)

#define LDS_GG(G, T) do { \
  const int gb_ = 131072 + (((T) * 32 + h * 16) << 2); \
  G[0] = *(const float4*)(smem + gb_); \
  G[1] = *(const float4*)(smem + gb_ + 16); \
  G[2] = *(const float4*)(smem + gb_ + 32); \
  G[3] = *(const float4*)(smem + gb_ + 48); \
} while (0)

// Exact streaming top-2 with index-embedded values.
// Invariant: m1 = max(S), m2 = 2nd-max(S) over all perturbed values seen.
// Per pair: med3(va,vb,m1) = the one of {va,vb,old-m1} that becomes 2nd.
#define TILE_BODY(T, CH, CL, G) do { \
  f32x16 acc0, acc1 = {};            /* acc0 init = permuted -0.5*c2 (regs) */ \
  acc0[0]  = G[0].x; acc0[1]  = G[0].y; acc0[2]  = G[0].z; acc0[3]  = G[0].w; \
  acc0[4]  = G[1].x; acc0[5]  = G[1].y; acc0[6]  = G[1].z; acc0[7]  = G[1].w; \
  acc0[8]  = G[2].x; acc0[9]  = G[2].y; acc0[10] = G[2].z; acc0[11] = G[2].w; \
  acc0[12] = G[3].x; acc0[13] = G[3].y; acc0[14] = G[3].z; acc0[15] = G[3].w; \
  acc0 = MFMA_B(CH[0], zh[0], acc0);  acc1 = MFMA_B(CH[1], zh[1], acc1); \
  acc0 = MFMA_B(CH[2], zh[2], acc0);  acc1 = MFMA_B(CH[3], zh[3], acc1); \
  acc0 = MFMA_B(CH[0], zl[0], acc0);  acc1 = MFMA_B(CH[1], zl[1], acc1); \
  acc0 = MFMA_B(CH[2], zl[2], acc0);  acc1 = MFMA_B(CH[3], zl[3], acc1); \
  acc0 = MFMA_B(CL[0], zh[0], acc0);  acc1 = MFMA_B(CL[1], zh[1], acc1); \
  acc0 = MFMA_B(CL[2], zh[2], acc0);  acc1 = MFMA_B(CL[3], zh[3], acc1); \
  const unsigned m1pre_bits = __float_as_uint(m1); \
  _Pragma("unroll") \
  for (int rp = 0; rp < 8; ++rp) { \
    float va = acc0[2 * rp]     + acc1[2 * rp]; \
    float vb = acc0[2 * rp + 1] + acc1[2 * rp + 1]; \
    va = __uint_as_float((__float_as_uint(va) & 0xFFFFFFF0u) \
                         | (unsigned)(15 - 2 * rp)); \
    vb = __uint_as_float((__float_as_uint(vb) & 0xFFFFFFF0u) \
                         | (unsigned)(14 - 2 * rp)); \
    float tmid = __builtin_amdgcn_fmed3f(va, vb, m1); \
    m1 = fmaxf(fmaxf(va, vb), m1); \
    m2 = fmaxf(m2, tmid); \
  } \
  if (__float_as_uint(m1) != m1pre_bits) tbest = (T); \
} while (0)

__global__ __launch_bounds__(512)
void vq_main(const float* __restrict__ z, const float* __restrict__ cbk,
             float* __restrict__ out, float* __restrict__ lossAcc,
             unsigned* __restrict__ cnt, unsigned* __restrict__ list, int N)
{
  extern __shared__ char smem[];

  const int tid  = threadIdx.x;
  const int lane = tid & 63;
  const int wave = tid >> 6;
  const int col  = lane & 31;    // this lane's z-row within the wave's 32 rows
  const int h    = lane >> 5;    // k-half / output split

  // ---- fill: convert codebook -> bf16 hi/lo frag-order tables + nhc2 ------
  // one thread = one codeword; CHUNKED (16 elems live at a time, no big
  // arrays -> no spill). c2 FMA chain order identical to R12 (bit-equal).
  {
    const int cw = tid;
    const float4* c4 = (const float4*)(cbk + (size_t)cw * D);
    const int T = cw >> 5, cc = cw & 31;
    float c2 = 0.f;
    #pragma unroll
    for (int sl = 0; sl < 4; ++sl) {
      float4 f0 = c4[4 * sl];     float4 f1 = c4[4 * sl + 1];
      float4 f2 = c4[4 * sl + 2]; float4 f3 = c4[4 * sl + 3];
      FMA4(c2, f0, f0); FMA4(c2, f1, f1); FMA4(c2, f2, f2); FMA4(c2, f3, f3);
      const float e[16] = {f0.x, f0.y, f0.z, f0.w, f1.x, f1.y, f1.z, f1.w,
                           f2.x, f2.y, f2.z, f2.w, f3.x, f3.y, f3.z, f3.w};
      #pragma unroll
      for (int h2 = 0; h2 < 2; ++h2) {
        s16x8 vh, vl;
        #pragma unroll
        for (int j = 0; j < 8; ++j) {
          unsigned short hb = f2bf(e[h2 * 8 + j]);
          float hf = __uint_as_float((unsigned)hb << 16);
          vh[j] = (short)hb;
          vl[j] = (short)f2bf(e[h2 * 8 + j] - hf);
        }
        const int a = T * 4096 + sl * 1024 + h2 * 512 + cc * 16;
        *(s16x8*)(smem + a) = vh;
        *(s16x8*)(smem + 65536 + a) = vl;
      }
    }
    // invert perm(r,h) = (r&3) + 8*(r>>2) + 4*h : arranged[t*32 + h*16 + r]
    const int ai = (T << 5) + (((cc >> 2) & 1) << 4) + ((cc >> 3) << 2) + (cc & 3);
    *(float*)(smem + 131072 + ai * 4) = -0.5f * c2;
  }
  __syncthreads();   // tables read-only afterwards: no more barriers

  float lacc = 0.f;

  #pragma unroll 1
  for (int it = 0; it < 4; ++it) {
    const long rowg = (long)blockIdx.x * 1024 + it * 256 + wave * 32 + col;

    // z row -> bf16 hi/lo B-frags. Lane holds k = 16s + 8h + j, j=0..7.
    const float4* zp4 = (const float4*)(z + (size_t)rowg * D);
    s16x8 zh[4], zl[4];
    #pragma unroll
    for (int s = 0; s < 4; ++s) {
      float4 p0 = zp4[4 * s + 2 * h];
      float4 p1 = zp4[4 * s + 2 * h + 1];
      float e[8] = {p0.x, p0.y, p0.z, p0.w, p1.x, p1.y, p1.z, p1.w};
      #pragma unroll
      for (int j = 0; j < 8; ++j) {
        unsigned short hb = f2bf(e[j]);
        float hf = __uint_as_float((unsigned)hb << 16);
        zh[s][j] = (short)hb;
        zl[s][j] = (short)f2bf(e[j] - hf);
      }
    }

    float m1 = -INFINITY, m2 = -INFINITY;
    int tbest = 0;

    // 1-tile-ahead LDS prefetch, double reg set (R8-verified pipeline).
    s16x8 chA[4], clA[4], chB[4], clB[4];
    float4 gA[4], gB[4];
    LDS_FRAGS(chA, clA, 0);  LDS_GG(gA, 0);
    LDS_FRAGS(chB, clB, 1);  LDS_GG(gB, 1);
    #pragma unroll 1
    for (int t = 0; t < 14; t += 2) {
      TILE_BODY(t, chA, clA, gA);
      LDS_FRAGS(chA, clA, t + 2);  LDS_GG(gA, t + 2);
      TILE_BODY(t + 1, chB, clB, gB);
      LDS_FRAGS(chB, clB, t + 3);  LDS_GG(gB, t + 3);
    }
    TILE_BODY(14, chA, clA, gA);
    TILE_BODY(15, chB, clB, gB);

    // winner r from the embedded bits; cw = (tbest<<5) + perm(r,h)
    const int rbest = 15 - (int)(__float_as_uint(m1) & 15u);
    int idx = (tbest << 5) + (h << 2) + (rbest & 3) + ((rbest >> 2) << 3);

    // combine the two k-halves (lane <-> lane^32); lower cw wins ties
    float om1  = __shfl_xor(m1, 32);
    float om2  = __shfl_xor(m2, 32);
    int   oidx = __shfl_xor(idx, 32);
    float nm2 = fmaxf(fminf(m1, om1), fmaxf(m2, om2));
    bool take = (om1 > m1) || ((om1 == m1) && (oidx < idx));
    if (take) { m1 = om1; idx = oidx; }
    m2 = nm2;

    if (m1 - m2 > STH) {
      // certain: provably the fp32 argmin. Epilogue ops identical to R4,
      // split across the lane pair (h picks the 32-element half of the row).
      const float4* qp = (const float4*)(cbk + (size_t)idx * D) + (h << 3);
      const float4* zp = (const float4*)(z + (size_t)rowg * D) + (h << 3);
      float4*       op = (float4*)(out + (size_t)rowg * D) + (h << 3);
      #pragma unroll
      for (int i = 0; i < 8; ++i) {
        float4 q = qp[i], zz = zp[i], u, qs;
        u.x = q.x - zz.x; u.y = q.y - zz.y; u.z = q.z - zz.z; u.w = q.w - zz.w;
        qs.x = zz.x + u.x; qs.y = zz.y + u.y; qs.z = zz.z + u.z; qs.w = zz.w + u.w;
        FMA4(lacc, u, u);
        op[i] = qs;
      }
      if (h == 0) (out + (size_t)N * D + 1)[rowg] = (float)idx;
    } else if (h == 0) {
      unsigned p = atomicAdd(cnt, 1u);     // flagged -> exact fallback kernel
      list[p] = (unsigned)rowg;
    }
  }

  // loss (certain rows): wave shuffle reduce -> one atomicAdd per wave.
  #pragma unroll
  for (int off = 32; off > 0; off >>= 1) lacc += __shfl_down(lacc, off, 64);
  if (lane == 0) atomicAdd(lossAcc, lacc);
}

// ---------------- fallback + finalize: wave-per-row exact R4 chains ---------
// Lane handles 8 consecutive codewords (k = lane*8+j); per-(row,k) the FMA
// chains are BIT-IDENTICAL to R4/R7 (c2: FMA4 over 16 float4s in order; dot:
// a0=even chunks / b0=odd chunks in order; d = fmaf(-2,dot,z2)+c2).
// Cross-lane merge keeps min-d, tie -> lowest k == numpy first-min.
// Loss finalized by the last B-block (A's adds visible by stream order).
__global__ __launch_bounds__(256)
void vq_fb(const float* __restrict__ z, const float* __restrict__ cbk,
           float* __restrict__ out, float* __restrict__ lossAcc,
           const unsigned* __restrict__ list, const unsigned* __restrict__ cntp,
           unsigned* __restrict__ done, int N)
{
  const unsigned cnt = *cntp;
  const int tid  = threadIdx.x;
  const int lane = tid & 63;
  const unsigned wid = (blockIdx.x * blockDim.x + tid) >> 6;
  const unsigned nw  = (gridDim.x * blockDim.x) >> 6;

  float lacc = 0.f;
  #pragma unroll 1
  for (unsigned p = wid; p < cnt; p += nw) {
    const size_t r0 = (size_t)list[p];

    const float4* zp = (const float4*)(z + r0 * D);
    float4 z0[D4];
    #pragma unroll
    for (int i = 0; i < D4; ++i) z0[i] = zp[i];
    float z2 = 0.f;
    #pragma unroll
    for (int i = 0; i < D4; ++i) FMA4(z2, z0[i], z0[i]);

    float best = INFINITY;
    int   bi = 0;
    #pragma unroll 1
    for (int j = 0; j < 8; ++j) {
      const int k = (lane << 3) + j;
      const float4* c4 = (const float4*)(cbk + (size_t)k * D);
      float4 cr[D4];
      #pragma unroll
      for (int i = 0; i < D4; ++i) cr[i] = c4[i];
      float c2 = 0.f;
      #pragma unroll
      for (int i = 0; i < D4; ++i) FMA4(c2, cr[i], cr[i]);
      float a0 = 0.f, b0 = 0.f;
      #pragma unroll
      for (int i = 0; i < 8; ++i) {
        FMA4(a0, z0[2 * i],     cr[2 * i]);
        FMA4(b0, z0[2 * i + 1], cr[2 * i + 1]);
      }
      float dot = a0 + b0;
      float d = fmaf(-2.f, dot, z2) + c2;
      if (d < best) { best = d; bi = k; }   // strict <, ascending k
    }

    #pragma unroll
    for (int off = 32; off > 0; off >>= 1) {
      float ob = __shfl_xor(best, off, 64);
      int  obi = __shfl_xor(bi, off, 64);
      if (ob < best || (ob == best && obi < bi)) { best = ob; bi = obi; }
    }

    if (lane == 0) {
      const float4* qp = (const float4*)(cbk + (size_t)bi * D);
      float4* o = (float4*)(out + r0 * D);
      #pragma unroll
      for (int i = 0; i < D4; ++i) {
        float4 q = qp[i], zz = z0[i], u, qs;
        u.x = q.x - zz.x; u.y = q.y - zz.y; u.z = q.z - zz.z; u.w = q.w - zz.w;
        qs.x = zz.x + u.x; qs.y = zz.y + u.y; qs.z = zz.z + u.z; qs.w = zz.w + u.w;
        FMA4(lacc, u, u);
        o[i] = qs;
      }
      (out + (size_t)N * D + 1)[r0] = (float)bi;
    }
  }

  // add this kernel's loss contributions, then last block finalizes
  #pragma unroll
  for (int off = 32; off > 0; off >>= 1) lacc += __shfl_down(lacc, off, 64);
  __shared__ float wsum[4];
  if (lane == 0) wsum[tid >> 6] = lacc;
  __syncthreads();
  if (tid == 0) {
    float s = wsum[0] + wsum[1] + wsum[2] + wsum[3];
    if (s != 0.f) atomicAdd(lossAcc, s);
    __threadfence();                               // publish before done-add
    unsigned d = atomicAdd(done, 1u);
    if (d == gridDim.x - 1) {                      // last block: all adds done
      float total = atomicAdd(lossAcc, 0.0f);      // device-scope atomic read
      out[(size_t)N * D] = 1.25f * (total / (float)((long)N * D));
    }
  }
}

extern "C" void kernel_launch(void* const* d_in, const int* in_sizes, int n_in,
                              void* d_out, int out_size, void* d_ws, size_t ws_size,
                              hipStream_t stream)
{
  const float* z   = (const float*)d_in[0];
  const float* cbk = (const float*)d_in[1];
  float* out = (float*)d_out;
  float* ws  = (float*)d_ws;
  const int N = in_sizes[0] / D;

  // ws layout (floats): [0]=lossAcc, [1]=flagCount, [2]=done, [64..)=flag list
  float*    lossAcc = ws;
  unsigned* cnt     = (unsigned*)(ws + 1);
  unsigned* done    = (unsigned*)(ws + 2);
  unsigned* list    = (unsigned*)(ws + 64);

  hipMemsetAsync(ws, 0, 12, stream);  // clears lossAcc + flagCount + done
  vq_main<<<N / 1024, 512, 133120, stream>>>(z, cbk, out, lossAcc, cnt, list, N);
  vq_fb<<<512, 256, 0, stream>>>(z, cbk, out, lossAcc, list, cnt, done, N);
}